// Round 1
// baseline (18.225 us; speedup 1.0000x reference)
//
#include <hip/hip_runtime.h>
#include <math.h>

#define BATCH 64
#define TLEN 8000
#define KDIM 4
#define NCHUNK 8
#define NPART 21   // 16 (M) + 4 (V) + 1 (mask sum)
#define POS_W 1.5f

__device__ __forceinline__ float log_sigmoid_f(float x) {
    // stable: min(x,0) - log1p(exp(-|x|))
    return fminf(x, 0.0f) - log1pf(__expf(-fabsf(x)));
}

__global__ __launch_bounds__(256) void pit_partial(
    const float* __restrict__ logits, const float* __restrict__ targets,
    const float* __restrict__ mask, float* __restrict__ ws)
{
    const int chunk = blockIdx.x;   // 0..NCHUNK-1
    const int b     = blockIdx.y;   // 0..BATCH-1
    const int tid   = threadIdx.x;
    const int tpc = (TLEN + NCHUNK - 1) / NCHUNK;   // 1000
    const int t0 = chunk * tpc;
    const int t1 = (t0 + tpc < TLEN) ? (t0 + tpc) : TLEN;

    float M[4][4] = {{0.f}};
    float V[4] = {0.f};
    float msum = 0.f;

    const float4* lg4 = (const float4*)(logits  + (size_t)b * TLEN * KDIM);
    const float4* tg4 = (const float4*)(targets + (size_t)b * TLEN * KDIM);
    const float*  mk  = mask + (size_t)b * TLEN;

    for (int t = t0 + tid; t < t1; t += 256) {
        float4 xv = lg4[t];
        float4 tv = tg4[t];
        float  m  = mk[t];
        float xs[4] = {xv.x, xv.y, xv.z, xv.w};
        float ts[4] = {tv.x, tv.y, tv.z, tv.w};
        msum += m;
        #pragma unroll
        for (int i = 0; i < 4; ++i) {
            float A  = log_sigmoid_f(xs[i]);
            float Bn = A - xs[i];          // log_sigmoid(-x) = log_sigmoid(x) - x
            float C  = POS_W * A - Bn;
            V[i] += m * Bn;
            float mc = m * C;
            #pragma unroll
            for (int j = 0; j < 4; ++j)
                M[i][j] += mc * ts[j];
        }
    }

    // deterministic block tree-reduction of 21 partials
    __shared__ float s[256][NPART];   // 21504 B
    #pragma unroll
    for (int i = 0; i < 4; ++i)
        #pragma unroll
        for (int j = 0; j < 4; ++j)
            s[tid][i*4+j] = M[i][j];
    #pragma unroll
    for (int i = 0; i < 4; ++i) s[tid][16+i] = V[i];
    s[tid][20] = msum;
    __syncthreads();
    for (int off = 128; off > 0; off >>= 1) {
        if (tid < off) {
            #pragma unroll
            for (int k = 0; k < NPART; ++k)
                s[tid][k] += s[tid + off][k];
        }
        __syncthreads();
    }
    if (tid < NPART)
        ws[((size_t)b * NCHUNK + chunk) * NPART + tid] = s[0][tid];
}

__global__ __launch_bounds__(64) void pit_final(
    const float* __restrict__ ws, float* __restrict__ out)
{
    const int b = threadIdx.x;  // 0..63, one lane per batch element
    float p[NPART];
    #pragma unroll
    for (int k = 0; k < NPART; ++k) p[k] = 0.f;
    #pragma unroll
    for (int c = 0; c < NCHUNK; ++c) {
        #pragma unroll
        for (int k = 0; k < NPART; ++k)
            p[k] += ws[((size_t)b * NCHUNK + c) * NPART + k];
    }
    const float denom = fmaxf(p[20], 1.0f);
    float cost[4][4];
    #pragma unroll
    for (int i = 0; i < 4; ++i)
        #pragma unroll
        for (int j = 0; j < 4; ++j)
            cost[i][j] = -(p[i*4 + j] + p[16 + i]) / denom;

    constexpr int PERMS[24][4] = {
        {0,1,2,3},{0,1,3,2},{0,2,1,3},{0,2,3,1},{0,3,1,2},{0,3,2,1},
        {1,0,2,3},{1,0,3,2},{1,2,0,3},{1,2,3,0},{1,3,0,2},{1,3,2,0},
        {2,0,1,3},{2,0,3,1},{2,1,0,3},{2,1,3,0},{2,3,0,1},{2,3,1,0},
        {3,0,1,2},{3,0,2,1},{3,1,0,2},{3,1,2,0},{3,2,0,1},{3,2,1,0}};
    float best = 3.4e38f;
    #pragma unroll
    for (int pi = 0; pi < 24; ++pi) {
        float s4 = cost[0][PERMS[pi][0]] + cost[1][PERMS[pi][1]]
                 + cost[2][PERMS[pi][2]] + cost[3][PERMS[pi][3]];
        best = fminf(best, s4);
    }
    float loss = best * 0.25f;

    // wave-64 reduce (sum), then mean over BATCH
    #pragma unroll
    for (int off = 32; off > 0; off >>= 1)
        loss += __shfl_down(loss, off);
    if (b == 0) out[0] = loss * (1.0f / BATCH);
}

extern "C" void kernel_launch(void* const* d_in, const int* in_sizes, int n_in,
                              void* d_out, int out_size, void* d_ws, size_t ws_size,
                              hipStream_t stream) {
    const float* logits  = (const float*)d_in[0];
    const float* targets = (const float*)d_in[1];
    const float* mask    = (const float*)d_in[2];
    float* out = (float*)d_out;
    float* ws  = (float*)d_ws;

    dim3 grid(NCHUNK, BATCH);
    pit_partial<<<grid, 256, 0, stream>>>(logits, targets, mask, ws);
    pit_final<<<1, 64, 0, stream>>>(ws, out);
}

// Round 2
// 13.503 us; speedup vs baseline: 1.3497x; 1.3497x over previous
//
#include <hip/hip_runtime.h>
#include <math.h>

#define BATCH 64
#define TLEN 8000
#define KDIM 4
#define NCHUNK 16
#define TPC (TLEN / NCHUNK)     // 500 frames per chunk
#define NPART 21                // 16 (M) + 4 (V) + 1 (mask sum)

// fast, stable log-sigmoid: min(x,0) - log(1 + exp(-|x|))
__device__ __forceinline__ float log_sigmoid_f(float x) {
    float e = __expf(-fabsf(x));
    return fminf(x, 0.0f) - __logf(1.0f + e);
}

__global__ __launch_bounds__(256) void pit_partial(
    const float* __restrict__ logits, const float* __restrict__ targets,
    const float* __restrict__ mask, float* __restrict__ ws)
{
    const int chunk = blockIdx.x;   // 0..NCHUNK-1
    const int b     = blockIdx.y;   // 0..BATCH-1
    const int tid   = threadIdx.x;
    const int t0    = chunk * TPC;

    float M[4][4] = {{0.f}};
    float V[4] = {0.f};
    float msum = 0.f;

    const float4* lg4 = (const float4*)(logits  + (size_t)b * TLEN * KDIM);
    const float4* tg4 = (const float4*)(targets + (size_t)b * TLEN * KDIM);
    const float*  mk  = mask + (size_t)b * TLEN;

    for (int t = t0 + tid; t < t0 + TPC; t += 256) {
        float4 xv = lg4[t];
        float4 tv = tg4[t];
        float  m  = mk[t];
        float xs[4] = {xv.x, xv.y, xv.z, xv.w};
        float ts[4] = {tv.x, tv.y, tv.z, tv.w};
        msum += m;
        #pragma unroll
        for (int i = 0; i < 4; ++i) {
            float A  = log_sigmoid_f(xs[i]);
            float Bn = A - xs[i];           // log_sigmoid(-x)
            float C  = fmaf(0.5f, A, xs[i]);// POS_W*A - Bn with POS_W=1.5
            V[i] = fmaf(m, Bn, V[i]);
            float mc = m * C;
            #pragma unroll
            for (int j = 0; j < 4; ++j)
                M[i][j] = fmaf(mc, ts[j], M[i][j]);
        }
    }

    // ---- 3-stage deterministic LDS reduction (2 syncthreads) ----
    __shared__ float red[256 * NPART];          // 21504 B
    __shared__ float red2[8 * NPART];
    #pragma unroll
    for (int i = 0; i < 4; ++i)
        #pragma unroll
        for (int j = 0; j < 4; ++j)
            red[tid * NPART + i * 4 + j] = M[i][j];
    #pragma unroll
    for (int i = 0; i < 4; ++i) red[tid * NPART + 16 + i] = V[i];
    red[tid * NPART + 20] = msum;
    __syncthreads();

    {   // 8 segments x 21 parts = 168 workers, each sums 32 rows
        const int seg = tid >> 5;
        const int k   = tid & 31;
        if (k < NPART) {
            float acc = 0.f;
            #pragma unroll
            for (int i = 0; i < 32; ++i)
                acc += red[(seg * 32 + i) * NPART + k];
            red2[seg * NPART + k] = acc;
        }
    }
    __syncthreads();

    if (tid < NPART) {
        float acc = 0.f;
        #pragma unroll
        for (int s = 0; s < 8; ++s)
            acc += red2[s * NPART + tid];
        // ws layout: [chunk][part][batch]  -> coalesced reads in pit_final
        ws[(chunk * NPART + tid) * BATCH + b] = acc;
    }
}

__global__ __launch_bounds__(64) void pit_final(
    const float* __restrict__ ws, float* __restrict__ out)
{
    const int b = threadIdx.x;  // one lane per batch element
    float p[NPART];
    #pragma unroll
    for (int k = 0; k < NPART; ++k) p[k] = 0.f;
    #pragma unroll
    for (int c = 0; c < NCHUNK; ++c)
        #pragma unroll
        for (int k = 0; k < NPART; ++k)
            p[k] += ws[(c * NPART + k) * BATCH + b];

    const float denom = fmaxf(p[20], 1.0f);
    float cost[4][4];
    #pragma unroll
    for (int i = 0; i < 4; ++i)
        #pragma unroll
        for (int j = 0; j < 4; ++j)
            cost[i][j] = -(p[i * 4 + j] + p[16 + i]) / denom;

    constexpr int PERMS[24][4] = {
        {0,1,2,3},{0,1,3,2},{0,2,1,3},{0,2,3,1},{0,3,1,2},{0,3,2,1},
        {1,0,2,3},{1,0,3,2},{1,2,0,3},{1,2,3,0},{1,3,0,2},{1,3,2,0},
        {2,0,1,3},{2,0,3,1},{2,1,0,3},{2,1,3,0},{2,3,0,1},{2,3,1,0},
        {3,0,1,2},{3,0,2,1},{3,1,0,2},{3,1,2,0},{3,2,0,1},{3,2,1,0}};
    float best = 3.4e38f;
    #pragma unroll
    for (int pi = 0; pi < 24; ++pi) {
        float s4 = cost[0][PERMS[pi][0]] + cost[1][PERMS[pi][1]]
                 + cost[2][PERMS[pi][2]] + cost[3][PERMS[pi][3]];
        best = fminf(best, s4);
    }
    float loss = best * 0.25f;

    #pragma unroll
    for (int off = 32; off > 0; off >>= 1)
        loss += __shfl_down(loss, off);
    if (b == 0) out[0] = loss * (1.0f / BATCH);
}

extern "C" void kernel_launch(void* const* d_in, const int* in_sizes, int n_in,
                              void* d_out, int out_size, void* d_ws, size_t ws_size,
                              hipStream_t stream) {
    const float* logits  = (const float*)d_in[0];
    const float* targets = (const float*)d_in[1];
    const float* mask    = (const float*)d_in[2];
    float* out = (float*)d_out;
    float* ws  = (float*)d_ws;

    dim3 grid(NCHUNK, BATCH);
    pit_partial<<<grid, 256, 0, stream>>>(logits, targets, mask, ws);
    pit_final<<<1, 64, 0, stream>>>(ws, out);
}